// Round 16
// baseline (330.555 us; speedup 1.0000x reference)
//
#include <hip/hip_runtime.h>
#include <math.h>

#define SDIM 512
#define BDIM 64
#define HDIM 512
#define TDIM 32
#define MTOT (SDIM * BDIM)

typedef __attribute__((ext_vector_type(8))) short bf16x8;
typedef __attribute__((ext_vector_type(4))) float f32x4;

// static device scratch
__device__ unsigned short g_w1hT[HDIM * HDIM];  // W1^T hi [n][k]
__device__ unsigned short g_w1lT[HDIM * HDIM];  // W1^T lo [n][k]
__device__ unsigned short g_w2hT[TDIM * HDIM];  // W2^T hi [t][k]
__device__ unsigned short g_w2lT[TDIM * HDIM];  // W2^T lo [t][k]
__device__ float g_em[(size_t)MTOT * TDIM];     // 4 MB emissions, b-major

__device__ __forceinline__ unsigned short f2bf(float x) {
  union { float f; unsigned int u; } v; v.f = x;
  unsigned int r = v.u + 0x7FFFu + ((v.u >> 16) & 1u);  // RNE
  return (unsigned short)(r >> 16);
}
__device__ __forceinline__ float bf2f(unsigned short h) {
  union { float f; unsigned int u; } v; v.u = ((unsigned int)h) << 16; return v.f;
}
__device__ __forceinline__ float fmax3(float a, float b, float c) {
  return fmaxf(fmaxf(a, b), c);  // fuses to v_max3_f32
}
__device__ __forceinline__ int imin3(int a, int b, int c) {
  int m = a < b ? a : b; return m < c ? m : c;  // fuses to v_min3_i32
}

// ---------------- W1/W2 split + transpose ----------------
__global__ void split_kernel(const float* __restrict__ W1, const float* __restrict__ W2) {
  const int n = blockIdx.x;
  const int k0 = threadIdx.x * 4;
  if (n < HDIM) {
    ushort4 h, l; float x;
    x = W1[(size_t)(k0 + 0) * HDIM + n]; h.x = f2bf(x); l.x = f2bf(x - bf2f(h.x));
    x = W1[(size_t)(k0 + 1) * HDIM + n]; h.y = f2bf(x); l.y = f2bf(x - bf2f(h.y));
    x = W1[(size_t)(k0 + 2) * HDIM + n]; h.z = f2bf(x); l.z = f2bf(x - bf2f(h.z));
    x = W1[(size_t)(k0 + 3) * HDIM + n]; h.w = f2bf(x); l.w = f2bf(x - bf2f(h.w));
    *(ushort4*)&g_w1hT[(size_t)n * HDIM + k0] = h;
    *(ushort4*)&g_w1lT[(size_t)n * HDIM + k0] = l;
  } else {
    const int t = n - HDIM;
    ushort4 h, l; float x;
    x = W2[(size_t)(k0 + 0) * TDIM + t]; h.x = f2bf(x); l.x = f2bf(x - bf2f(h.x));
    x = W2[(size_t)(k0 + 1) * TDIM + t]; h.y = f2bf(x); l.y = f2bf(x - bf2f(h.y));
    x = W2[(size_t)(k0 + 2) * TDIM + t]; h.z = f2bf(x); l.z = f2bf(x - bf2f(h.z));
    x = W2[(size_t)(k0 + 3) * TDIM + t]; h.w = f2bf(x); l.w = f2bf(x - bf2f(h.w));
    *(ushort4*)&g_w2hT[(size_t)t * HDIM + k0] = h;
    *(ushort4*)&g_w2lT[(size_t)t * HDIM + k0] = l;
  }
}

// ---------------- Fused emissions (r15 version, proven ~108 us, absmax 0) ----------------
__global__ __launch_bounds__(256) void emis_kernel(
    const float* __restrict__ hidden, const float* __restrict__ b1,
    const float* __restrict__ b2)
{
  __shared__ unsigned short lAh[64][40];
  __shared__ unsigned short lAl[64][40];
  __shared__ unsigned short lBh[128][40];
  __shared__ unsigned short lBl[128][40];
  __shared__ unsigned short H1h[64][136];
  __shared__ unsigned short H1l[64][136];

  const int tid = threadIdx.x;
  const int s = blockIdx.x;
  const int row0 = s * 64;
  const int wave = tid >> 6;
  const int lane = tid & 63;
  const int l15 = lane & 15;
  const int l4 = lane >> 4;
  const int wr1 = (wave >> 1) * 32;
  const int wc1 = (wave & 1) * 64;

  f32x4 acc_em[2];
  acc_em[0] = (f32x4)(0.f);
  acc_em[1] = (f32x4)(0.f);

  for (int jcb = 0; jcb < 4; ++jcb) {
    const int jc = jcb * 128;

    f32x4 acc1[2][4];
#pragma unroll
    for (int i = 0; i < 2; ++i)
#pragma unroll
      for (int j = 0; j < 4; ++j) acc1[i][j] = (f32x4)(0.f);

    for (int k0 = 0; k0 < HDIM; k0 += 32) {
#pragma unroll
      for (int i = 0; i < 2; ++i) {
        int f4 = tid + 256 * i;
        int r = f4 >> 3, q = f4 & 7;
        float4 v = *(const float4*)&hidden[(size_t)(row0 + r) * HDIM + k0 + 4 * q];
        ushort4 h, l;
        h.x = f2bf(v.x); l.x = f2bf(v.x - bf2f(h.x));
        h.y = f2bf(v.y); l.y = f2bf(v.y - bf2f(h.y));
        h.z = f2bf(v.z); l.z = f2bf(v.z - bf2f(h.z));
        h.w = f2bf(v.w); l.w = f2bf(v.w - bf2f(h.w));
        *(ushort4*)&lAh[r][4 * q] = h;
        *(ushort4*)&lAl[r][4 * q] = l;
      }
#pragma unroll
      for (int i = 0; i < 2; ++i) {
        int f8 = tid + 256 * i;
        int nl = f8 >> 2, kq8 = f8 & 3;
        *(uint4*)&lBh[nl][8 * kq8] =
            *(const uint4*)&g_w1hT[(size_t)(jc + nl) * HDIM + k0 + 8 * kq8];
        *(uint4*)&lBl[nl][8 * kq8] =
            *(const uint4*)&g_w1lT[(size_t)(jc + nl) * HDIM + k0 + 8 * kq8];
      }
      __syncthreads();

      bf16x8 aH[2], aL[2];
#pragma unroll
      for (int i = 0; i < 2; ++i) {
        aH[i] = *(const bf16x8*)&lAh[wr1 + 16 * i + l15][8 * l4];
        aL[i] = *(const bf16x8*)&lAl[wr1 + 16 * i + l15][8 * l4];
      }
#pragma unroll
      for (int j = 0; j < 4; ++j) {
        bf16x8 bH = *(const bf16x8*)&lBh[wc1 + 16 * j + l15][8 * l4];
        bf16x8 bL = *(const bf16x8*)&lBl[wc1 + 16 * j + l15][8 * l4];
#pragma unroll
        for (int i = 0; i < 2; ++i) {
          acc1[i][j] = __builtin_amdgcn_mfma_f32_16x16x32_bf16(aH[i], bH, acc1[i][j], 0, 0, 0);
          acc1[i][j] = __builtin_amdgcn_mfma_f32_16x16x32_bf16(aH[i], bL, acc1[i][j], 0, 0, 0);
          acc1[i][j] = __builtin_amdgcn_mfma_f32_16x16x32_bf16(aL[i], bH, acc1[i][j], 0, 0, 0);
        }
      }
      __syncthreads();
    }

#pragma unroll
    for (int j = 0; j < 4; ++j) {
      const int col = wc1 + 16 * j + l15;
      const float bv = b1[jc + col];
#pragma unroll
      for (int i = 0; i < 2; ++i) {
#pragma unroll
        for (int r = 0; r < 4; ++r) {
          int lrow = wr1 + 16 * i + 4 * l4 + r;
          float h = 1.f / (1.f + __expf(-(acc1[i][j][r] + bv)));
          unsigned short hh = f2bf(h);
          unsigned short hl = f2bf(h - bf2f(hh));
          H1h[lrow][col] = hh;
          H1l[lrow][col] = hl;
        }
      }
    }
    __syncthreads();

#pragma unroll
    for (int ks = 0; ks < 4; ++ks) {
      bf16x8 aH2 = *(const bf16x8*)&H1h[16 * wave + l15][32 * ks + 8 * l4];
      bf16x8 aL2 = *(const bf16x8*)&H1l[16 * wave + l15][32 * ks + 8 * l4];
#pragma unroll
      for (int j2 = 0; j2 < 2; ++j2) {
        const size_t wo = (size_t)(16 * j2 + l15) * HDIM + jc + 32 * ks + 8 * l4;
        bf16x8 bH2 = *(const bf16x8*)&g_w2hT[wo];
        bf16x8 bL2 = *(const bf16x8*)&g_w2lT[wo];
        acc_em[j2] = __builtin_amdgcn_mfma_f32_16x16x32_bf16(aH2, bH2, acc_em[j2], 0, 0, 0);
        acc_em[j2] = __builtin_amdgcn_mfma_f32_16x16x32_bf16(aH2, bL2, acc_em[j2], 0, 0, 0);
        acc_em[j2] = __builtin_amdgcn_mfma_f32_16x16x32_bf16(aL2, bH2, acc_em[j2], 0, 0, 0);
      }
    }
    __syncthreads();
  }

#pragma unroll
  for (int j2 = 0; j2 < 2; ++j2) {
    const int t = 16 * j2 + l15;
    const float bv = b2[t];
#pragma unroll
    for (int r = 0; r < 4; ++r) {
      int b = 16 * wave + 4 * l4 + r;
      g_em[((size_t)b * SDIM + s) * TDIM + t] = acc_em[j2][r] + bv;
    }
  }
}

// ---------------- Viterbi v10: 2 chains/wave, v7 h-split step, interleaved streams ----------------
__global__ __launch_bounds__(64) void viterbi_kernel(
    const int* __restrict__ lens, const float* __restrict__ trans,
    float* __restrict__ out)
{
  __shared__ float fvLA[64];
  __shared__ float fvLB[64];
  __shared__ unsigned int bps32[2][SDIM / 4][TDIM];  // 32 KB
  const int lane = threadIdx.x;
  const int c = lane & 31;
  const int h = lane >> 5;
  const int p0 = 16 * h;  // this half's prev range
  const int bA = 2 * blockIdx.x;
  const int bB = bA + 1;

  // tr[j] = trans[c][p0 + j] (shared by both chains)
  float tr[16];
#pragma unroll
  for (int j = 0; j < 16; j += 4) {
    float4 t4 = *(const float4*)&trans[c * TDIM + p0 + j];
    tr[j] = t4.x; tr[j + 1] = t4.y; tr[j + 2] = t4.z; tr[j + 3] = t4.w;
  }

  int lenA, lenB;
  { const int* p32 = lens;
    if (p32[1] == 0) {
      lenA = (int)((const long long*)lens)[bA];
      lenB = (int)((const long long*)lens)[bB];
    } else { lenA = p32[bA]; lenB = p32[bB]; } }

  const float* emcA = g_em + (size_t)bA * SDIM * TDIM + c;
  const float* emcB = g_em + (size_t)bB * SDIM * TDIM + c;

  float fvA = emcA[0];  // t = 0 (dup across halves)
  float fvB = emcB[0];
  fvLA[lane] = fvA;
  fvLB[lane] = fvB;

  // 12-deep register prefetch of em for both chains (t = 1..12)
  float ebA[12], ebB[12];
#pragma unroll
  for (int j = 0; j < 12; ++j) {
    ebA[j] = emcA[(size_t)(1 + j) * TDIM];
    ebB[j] = emcB[(size_t)(1 + j) * TDIM];
  }

  unsigned int bpkA = 0u, bpkB = 0u;

  // super-step: chain A and B independent dep chains in one basic block.
  // per chain = v7's proven step: 4 ds_read, 16 adds, max3 tree, shfl_xor
  // value merge, branchless freeze, eq+min3 index, packed bps.
#define VSTEP(T, PH, EVA, EVB)                                                 \
  {                                                                            \
    float4 aq0 = *(const float4*)&fvLA[p0];                                    \
    float4 aq1 = *(const float4*)&fvLA[p0 + 4];                                \
    float4 aq2 = *(const float4*)&fvLA[p0 + 8];                                \
    float4 aq3 = *(const float4*)&fvLA[p0 + 12];                               \
    float4 bq0 = *(const float4*)&fvLB[p0];                                    \
    float4 bq1 = *(const float4*)&fvLB[p0 + 4];                                \
    float4 bq2 = *(const float4*)&fvLB[p0 + 8];                                \
    float4 bq3 = *(const float4*)&fvLB[p0 + 12];                               \
    float svA[16], svB[16];                                                    \
    svA[0] = aq0.x + tr[0];  svA[1] = aq0.y + tr[1];                           \
    svA[2] = aq0.z + tr[2];  svA[3] = aq0.w + tr[3];                           \
    svA[4] = aq1.x + tr[4];  svA[5] = aq1.y + tr[5];                           \
    svA[6] = aq1.z + tr[6];  svA[7] = aq1.w + tr[7];                           \
    svA[8] = aq2.x + tr[8];  svA[9] = aq2.y + tr[9];                           \
    svA[10] = aq2.z + tr[10]; svA[11] = aq2.w + tr[11];                        \
    svA[12] = aq3.x + tr[12]; svA[13] = aq3.y + tr[13];                        \
    svA[14] = aq3.z + tr[14]; svA[15] = aq3.w + tr[15];                        \
    svB[0] = bq0.x + tr[0];  svB[1] = bq0.y + tr[1];                           \
    svB[2] = bq0.z + tr[2];  svB[3] = bq0.w + tr[3];                           \
    svB[4] = bq1.x + tr[4];  svB[5] = bq1.y + tr[5];                           \
    svB[6] = bq1.z + tr[6];  svB[7] = bq1.w + tr[7];                           \
    svB[8] = bq2.x + tr[8];  svB[9] = bq2.y + tr[9];                           \
    svB[10] = bq2.z + tr[10]; svB[11] = bq2.w + tr[11];                        \
    svB[12] = bq3.x + tr[12]; svB[13] = bq3.y + tr[13];                        \
    svB[14] = bq3.z + tr[14]; svB[15] = bq3.w + tr[15];                        \
    float lA0 = fmax3(svA[0], svA[1], svA[2]);                                 \
    float lA1 = fmax3(svA[3], svA[4], svA[5]);                                 \
    float lA2 = fmax3(svA[6], svA[7], svA[8]);                                 \
    float lA3 = fmax3(svA[9], svA[10], svA[11]);                               \
    float lA4 = fmax3(svA[12], svA[13], svA[14]);                              \
    float mhA = fmaxf(fmax3(lA0, lA1, lA2), fmax3(lA3, lA4, svA[15]));         \
    float lB0 = fmax3(svB[0], svB[1], svB[2]);                                 \
    float lB1 = fmax3(svB[3], svB[4], svB[5]);                                 \
    float lB2 = fmax3(svB[6], svB[7], svB[8]);                                 \
    float lB3 = fmax3(svB[9], svB[10], svB[11]);                               \
    float lB4 = fmax3(svB[12], svB[13], svB[14]);                              \
    float mhB = fmaxf(fmax3(lB0, lB1, lB2), fmax3(lB3, lB4, svB[15]));         \
    float moA = __shfl_xor(mhA, 32, 64);                                       \
    float moB = __shfl_xor(mhB, 32, 64);                                       \
    float m0A = fmaxf(mhA, moA);                                               \
    float m0B = fmaxf(mhB, moB);                                               \
    const bool actA = (T) < lenA;                                              \
    const bool actB = (T) < lenB;                                              \
    fvA = actA ? (m0A + (EVA)) : fvA;                                          \
    fvB = actB ? (m0B + (EVB)) : fvB;                                          \
    fvLA[lane] = fvA;                                                          \
    fvLB[lane] = fvB;                                                          \
    int iA_[16], iB_[16];                                                      \
    _Pragma("unroll")                                                          \
    for (int j = 0; j < 16; ++j) iA_[j] = (svA[j] == m0A) ? j : 63;            \
    _Pragma("unroll")                                                          \
    for (int j = 0; j < 16; ++j) iB_[j] = (svB[j] == m0B) ? j : 63;            \
    int uA0 = imin3(iA_[0], iA_[1], iA_[2]);                                   \
    int uA1 = imin3(iA_[3], iA_[4], iA_[5]);                                   \
    int uA2 = imin3(iA_[6], iA_[7], iA_[8]);                                   \
    int uA3 = imin3(iA_[9], iA_[10], iA_[11]);                                 \
    int uA4 = imin3(iA_[12], iA_[13], iA_[14]);                                \
    int jmA = imin3(imin3(uA0, uA1, uA2), imin3(uA3, uA4, iA_[15]), 63);       \
    int uB0 = imin3(iB_[0], iB_[1], iB_[2]);                                   \
    int uB1 = imin3(iB_[3], iB_[4], iB_[5]);                                   \
    int uB2 = imin3(iB_[6], iB_[7], iB_[8]);                                   \
    int uB3 = imin3(iB_[9], iB_[10], iB_[11]);                                 \
    int uB4 = imin3(iB_[12], iB_[13], iB_[14]);                                \
    int jmB = imin3(imin3(uB0, uB1, uB2), imin3(uB3, uB4, iB_[15]), 63);       \
    int giA = (jmA == 63) ? 255 : (p0 + jmA);                                  \
    int giB = (jmB == 63) ? 255 : (p0 + jmB);                                  \
    int goA = __shfl_xor(giA, 32, 64);                                         \
    int goB = __shfl_xor(giB, 32, 64);                                         \
    int imA = giA < goA ? giA : goA;                                           \
    int imB = giB < goB ? giB : goB;                                           \
    int bpA = actA ? imA : c;                                                  \
    int bpB = actB ? imB : c;                                                  \
    bpkA |= (unsigned)bpA << (8 * (PH));                                       \
    bpkB |= (unsigned)bpB << (8 * (PH));                                       \
    if ((PH) == 3) {                                                           \
      bps32[0][(T) >> 2][c] = bpkA;                                            \
      bps32[1][(T) >> 2][c] = bpkB;                                            \
      bpkA = 0u; bpkB = 0u;                                                    \
    }                                                                          \
  }

#define LOADQ(BASE, T0)                                                        \
  {                                                                            \
    _Pragma("unroll")                                                          \
    for (int j = 0; j < 4; ++j) {                                              \
      int lt = (T0) + j; lt = lt > (SDIM - 1) ? (SDIM - 1) : lt;               \
      ebA[(BASE) + j] = emcA[(size_t)lt * TDIM];                               \
      ebB[(BASE) + j] = emcB[(size_t)lt * TDIM];                               \
    }                                                                          \
  }

  {
    int tq = 1;
    for (; tq <= SDIM - 19; tq += 12) {  // t = 1..504
      VSTEP(tq + 0, 1, ebA[0], ebB[0]) VSTEP(tq + 1, 2, ebA[1], ebB[1])
      VSTEP(tq + 2, 3, ebA[2], ebB[2]) VSTEP(tq + 3, 0, ebA[3], ebB[3])
      LOADQ(0, tq + 12)
      VSTEP(tq + 4, 1, ebA[4], ebB[4]) VSTEP(tq + 5, 2, ebA[5], ebB[5])
      VSTEP(tq + 6, 3, ebA[6], ebB[6]) VSTEP(tq + 7, 0, ebA[7], ebB[7])
      LOADQ(4, tq + 16)
      VSTEP(tq + 8, 1, ebA[8], ebB[8]) VSTEP(tq + 9, 2, ebA[9], ebB[9])
      VSTEP(tq + 10, 3, ebA[10], ebB[10]) VSTEP(tq + 11, 0, ebA[11], ebB[11])
      LOADQ(8, tq + 20)
    }
    // tail: t = 505..511
    VSTEP(505, 1, ebA[0], ebB[0]) VSTEP(506, 2, ebA[1], ebB[1])
    VSTEP(507, 3, ebA[2], ebB[2]) VSTEP(508, 0, ebA[3], ebB[3])
    VSTEP(509, 1, ebA[4], ebB[4]) VSTEP(510, 2, ebA[5], ebB[5])
    VSTEP(511, 3, ebA[6], ebB[6])
  }
#undef VSTEP
#undef LOADQ

  // final argmax per chain (values dup across halves; width-32 reduce)
  float bsA = fvA; int biA = c;
  float bsB = fvB; int biB = c;
#pragma unroll
  for (int off = 16; off > 0; off >>= 1) {
    float oa = __shfl_down(bsA, off, 32); int ja = __shfl_down(biA, off, 32);
    if (oa > bsA || (oa == bsA && ja < biA)) { bsA = oa; biA = ja; }
    float ob = __shfl_down(bsB, off, 32); int jb = __shfl_down(biB, off, 32);
    if (ob > bsB || (ob == bsB && jb < biB)) { bsB = ob; biB = jb; }
  }
  bsA = __shfl(bsA, 0, 64); int tagA = __shfl(biA, 0, 64);
  bsB = __shfl(bsB, 0, 64); int tagB = __shfl(biB, 0, 64);

  if (lane == 0) {
    out[(size_t)SDIM * BDIM + bA] = bsA;
    out[(size_t)SDIM * BDIM + bB] = bsB;
    out[(size_t)(SDIM - 1) * BDIM + bA] = (float)tagA;
    out[(size_t)(SDIM - 1) * BDIM + bB] = (float)tagB;
  }

  // scalar backtrack, both chains interleaved (tagA/tagB uniform)
  unsigned bwAn = bps32[0][SDIM / 4 - 1][c];
  unsigned bwBn = bps32[1][SDIM / 4 - 1][c];
  for (int w = SDIM / 4 - 1; w >= 0; --w) {
    unsigned bwA = bwAn, bwB = bwBn;
    if (w > 0) {
      bwAn = bps32[0][w - 1][c];
      bwBn = bps32[1][w - 1][c];
    }
#pragma unroll
    for (int j = 3; j >= 0; --j) {
      int t = 4 * w + j;
      if (t < 1) continue;
      unsigned wa = (unsigned)__builtin_amdgcn_readlane((int)bwA, tagA);
      unsigned wb = (unsigned)__builtin_amdgcn_readlane((int)bwB, tagB);
      tagA = (int)((wa >> (8 * j)) & 255u);
      tagB = (int)((wb >> (8 * j)) & 255u);
      if (lane == 0) {
        out[(size_t)(t - 1) * BDIM + bA] = (float)tagA;
        out[(size_t)(t - 1) * BDIM + bB] = (float)tagB;
      }
    }
  }
}

// ---------------- host ----------------
static int find_by_size(const int* in_sizes, int n_in, int sz, int fb) {
  for (int i = 0; i < n_in; ++i) if (in_sizes[i] == sz) return i;
  return fb;
}

extern "C" void kernel_launch(void* const* d_in, const int* in_sizes, int n_in,
                              void* d_out, int out_size, void* d_ws, size_t ws_size,
                              hipStream_t stream) {
  const int i_hidden = find_by_size(in_sizes, n_in, SDIM * BDIM * HDIM, 0);
  const int i_lens   = find_by_size(in_sizes, n_in, BDIM, 1);
  const int i_W1     = find_by_size(in_sizes, n_in, HDIM * HDIM, 3);
  const int i_b1     = find_by_size(in_sizes, n_in, HDIM, 4);
  const int i_W2     = find_by_size(in_sizes, n_in, HDIM * TDIM, 5);
  const int i_b2     = find_by_size(in_sizes, n_in, TDIM, 6);
  const int i_tr     = find_by_size(in_sizes, n_in, TDIM * TDIM, 7);

  const float* hidden = (const float*)d_in[i_hidden];
  const int*   lens   = (const int*)d_in[i_lens];
  const float* W1     = (const float*)d_in[i_W1];
  const float* b1     = (const float*)d_in[i_b1];
  const float* W2     = (const float*)d_in[i_W2];
  const float* b2     = (const float*)d_in[i_b2];
  const float* trans  = (const float*)d_in[i_tr];
  float* out = (float*)d_out;

  split_kernel<<<HDIM + TDIM, 128, 0, stream>>>(W1, W2);
  emis_kernel<<<SDIM, 256, 0, stream>>>(hidden, b1, b2);
  viterbi_kernel<<<BDIM / 2, 64, 0, stream>>>(lens, trans, out);
}